// Round 2
// baseline (501.545 us; speedup 1.0000x reference)
//
#include <hip/hip_runtime.h>
#include <hip/hip_bf16.h>
#include <stdint.h>

#define B_SZ   4096
#define TWO_B  8192
#define D_DIM  2048
#define N_TOT  15000000
#define RHO    0.8f

typedef __attribute__((ext_vector_type(8))) __bf16 bf16x8;
typedef __attribute__((ext_vector_type(4))) float f32x4;
typedef unsigned short ushort_t;

// ---------- helpers ----------
__device__ __forceinline__ ushort_t f2bf(float v) {
    __hip_bfloat16 h = __float2bfloat16(v);
    return *reinterpret_cast<ushort_t*>(&h);
}
__device__ __forceinline__ float bf2f(unsigned int u16) {
    return __uint_as_float(u16 << 16);
}
__device__ __forceinline__ float waveReduceSum(float v) {
#pragma unroll
    for (int off = 32; off >= 1; off >>= 1) v += __shfl_down(v, off, 64);
    return v;
}
__device__ __forceinline__ void gload_lds16(const void* g, void* l) {
    __builtin_amdgcn_global_load_lds(
        (const __attribute__((address_space(1))) void*)(uintptr_t)g,
        (__attribute__((address_space(3))) void*)(uintptr_t)l,
        16, 0, 0);
}

// ---------- kernel 1: normalize rows -> bf16 ----------
__global__ __launch_bounds__(256) void knorm(const float* __restrict__ feat,
                                             ushort_t* __restrict__ fbf) {
    int row = blockIdx.x;
    int tid = threadIdx.x;
    const float4* fr = reinterpret_cast<const float4*>(feat + (size_t)row * D_DIM);
    float4 a = fr[tid * 2 + 0];
    float4 b = fr[tid * 2 + 1];
    float ss = a.x*a.x + a.y*a.y + a.z*a.z + a.w*a.w
             + b.x*b.x + b.y*b.y + b.z*b.z + b.w*b.w;
    ss = waveReduceSum(ss);
    __shared__ float wsum[4];
    if ((tid & 63) == 0) wsum[tid >> 6] = ss;
    __syncthreads();
    float tot = wsum[0] + wsum[1] + wsum[2] + wsum[3];
    float inv = 1.0f / fmaxf(sqrtf(tot), 1e-12f);
    uint4 o;
    o.x = (unsigned)f2bf(a.x * inv) | ((unsigned)f2bf(a.y * inv) << 16);
    o.y = (unsigned)f2bf(a.z * inv) | ((unsigned)f2bf(a.w * inv) << 16);
    o.z = (unsigned)f2bf(b.x * inv) | ((unsigned)f2bf(b.y * inv) << 16);
    o.w = (unsigned)f2bf(b.z * inv) | ((unsigned)f2bf(b.w * inv) << 16);
    reinterpret_cast<uint4*>(fbf + (size_t)row * D_DIM)[tid] = o;
}

// ---------- kernel 2: inv_tau per sim row ----------
__global__ void ktau(const float* __restrict__ tau_buf, const int* __restrict__ index,
                     float* __restrict__ inv_tau_rows) {
    int i = blockIdx.x * blockDim.x + threadIdx.x;
    if (i < TWO_B) inv_tau_rows[i] = 1.0f / tau_buf[index[i & (B_SZ - 1)]];
}

// ---------- kernel 3: positive-pair dot (rows i and i+B of bf16 f) ----------
__global__ __launch_bounds__(256) void kpos(const ushort_t* __restrict__ fbf,
                                            float* __restrict__ posdot) {
    int i = blockIdx.x;
    int tid = threadIdx.x;
    const uint4* r1 = reinterpret_cast<const uint4*>(fbf + (size_t)i * D_DIM);
    const uint4* r2 = reinterpret_cast<const uint4*>(fbf + (size_t)(i + B_SZ) * D_DIM);
    uint4 a = r1[tid], b = r2[tid];
    float s = 0.f;
    unsigned ua[4] = {a.x, a.y, a.z, a.w};
    unsigned ub[4] = {b.x, b.y, b.z, b.w};
#pragma unroll
    for (int k = 0; k < 4; ++k) {
        s += bf2f(ua[k] & 0xffffu) * bf2f(ub[k] & 0xffffu);
        s += bf2f(ua[k] >> 16)     * bf2f(ub[k] >> 16);
    }
    s = waveReduceSum(s);
    __shared__ float wsum[4];
    if ((tid & 63) == 0) wsum[tid >> 6] = s;
    __syncthreads();
    if (tid == 0) posdot[i] = wsum[0] + wsum[1] + wsum[2] + wsum[3];
}

// ---------- kernel 4: Gram GEMM + fused masked-exp row reductions ----------
// 128x128 tile, BK=32, 4 waves (2x2), each wave 64x64 via 4x4 frags of 16x16x32.
// Partials: per row, per 64-col half-tile -> Epart/Fpart[row*128 + cb*2 + wc].
__global__ __launch_bounds__(256) void kgram(const ushort_t* __restrict__ fbf,
                                             const float* __restrict__ inv_tau_rows,
                                             float* __restrict__ Epart,
                                             float* __restrict__ Fpart) {
    const int cb = blockIdx.x;       // column block [0,64)
    const int rb = blockIdx.y;       // row block    [0,64)
    const int tid = threadIdx.x;
    const int lane = tid & 63;
    const int w = tid >> 6;
    const int wr = w >> 1, wc = w & 1;
    const int r0 = rb * 128, c0 = cb * 128;

    __shared__ alignas(16) ushort_t As[128 * 32];
    __shared__ alignas(16) ushort_t Bs[128 * 32];

    f32x4 acc[4][4] = {};

    const int arow = tid >> 2;           // 0..63
    const int acol = (tid & 3) * 8;      // 0,8,16,24
    const int krow = (lane >> 4) * 8;    // k offset for frag loads

    for (int k0 = 0; k0 < D_DIM; k0 += 32) {
        __syncthreads();
        gload_lds16(fbf + (size_t)(r0 + arow) * D_DIM + k0 + acol,      &As[tid * 8]);
        gload_lds16(fbf + (size_t)(r0 + arow + 64) * D_DIM + k0 + acol, &As[tid * 8 + 2048]);
        gload_lds16(fbf + (size_t)(c0 + arow) * D_DIM + k0 + acol,      &Bs[tid * 8]);
        gload_lds16(fbf + (size_t)(c0 + arow + 64) * D_DIM + k0 + acol, &Bs[tid * 8 + 2048]);
        __syncthreads();

        bf16x8 af[4], bfr[4];
#pragma unroll
        for (int m = 0; m < 4; ++m)
            af[m] = *reinterpret_cast<const bf16x8*>(&As[(wr * 64 + m * 16 + (lane & 15)) * 32 + krow]);
#pragma unroll
        for (int n = 0; n < 4; ++n)
            bfr[n] = *reinterpret_cast<const bf16x8*>(&Bs[(wc * 64 + n * 16 + (lane & 15)) * 32 + krow]);
#pragma unroll
        for (int m = 0; m < 4; ++m)
#pragma unroll
            for (int n = 0; n < 4; ++n)
                acc[m][n] = __builtin_amdgcn_mfma_f32_16x16x32_bf16(af[m], bfr[n], acc[m][n], 0, 0, 0);
    }

    // Epilogue: masked exp, per-row partial sums over this wave's 64-col half.
#pragma unroll
    for (int m = 0; m < 4; ++m) {
#pragma unroll
        for (int r = 0; r < 4; ++r) {
            int row = r0 + wr * 64 + m * 16 + ((lane >> 4) << 2) + r;
            float it = inv_tau_rows[row];
            float esum = 0.f, fsum = 0.f;
#pragma unroll
            for (int n = 0; n < 4; ++n) {
                int col = c0 + wc * 64 + n * 16 + (lane & 15);
                float v = acc[m][n][r];
                if (((row ^ col) & (B_SZ - 1)) != 0) {   // mask: not same index mod B
                    float e = __expf(v * it);
                    esum += e;
                    fsum += e * v;
                }
            }
#pragma unroll
            for (int off = 1; off < 16; off <<= 1) {
                esum += __shfl_xor(esum, off, 64);
                fsum += __shfl_xor(fsum, off, 64);
            }
            if ((lane & 15) == 0) {
                Epart[(size_t)row * 128 + cb * 2 + wc] = esum;
                Fpart[(size_t)row * 128 + cb * 2 + wc] = fsum;
            }
        }
    }
}

// ---------- kernel 5: bulk copy s/u/tau -> out ----------
__global__ void kcopy(const float* __restrict__ s, const float* __restrict__ u,
                      const float* __restrict__ tau, float* __restrict__ out) {
    size_t i = (size_t)blockIdx.x * blockDim.x + threadIdx.x;
    size_t stride = (size_t)gridDim.x * blockDim.x;
    for (; i < N_TOT; i += stride) {
        out[1 + i] = s[i];
        out[1 + (size_t)N_TOT + i] = u[i];
        out[1 + 2 * (size_t)N_TOT + i] = tau[i];
    }
}

// ---------- kernel 6: finalize per positive pair ----------
__global__ __launch_bounds__(64) void kfin(const float* __restrict__ Epart,
                                           const float* __restrict__ Fpart,
                                           const float* __restrict__ posdot,
                                           const float* __restrict__ s,
                                           const float* __restrict__ tau_buf,
                                           const float* __restrict__ u_buf,
                                           const int* __restrict__ index,
                                           const int* __restrict__ epoch_p,
                                           float* __restrict__ out) {
    int i = blockIdx.x;     // [0, B)
    int lane = threadIdx.x; // [0, 64)
    float e1 = Epart[(size_t)i * 128 + lane]            + Epart[(size_t)i * 128 + 64 + lane];
    float f1 = Fpart[(size_t)i * 128 + lane]            + Fpart[(size_t)i * 128 + 64 + lane];
    float e2 = Epart[(size_t)(i + B_SZ) * 128 + lane]   + Epart[(size_t)(i + B_SZ) * 128 + 64 + lane];
    float f2 = Fpart[(size_t)(i + B_SZ) * 128 + lane]   + Fpart[(size_t)(i + B_SZ) * 128 + 64 + lane];
    e1 = waveReduceSum(e1);
    f1 = waveReduceSum(f1);
    e2 = waveReduceSum(e2);
    f2 = waveReduceSum(f2);

    // numpy scatter semantics: last occurrence of a duplicate index wins
    int idx = index[i];
    bool dup = false;
    for (int j = i + 1 + lane; j < B_SZ; j += 64)
        if (index[j] == idx) dup = true;
    unsigned long long ball = __ballot(dup);

    if (lane == 0) {
        const float num_neg = 2.0f * B_SZ - 2.0f;
        float g1 = e1 / num_neg, g2 = e2 / num_neg;
        float s_old = s[idx];
        float tau_i = tau_buf[idx];
        float u_old = u_buf[idx];
        int ep = *epoch_p;
        float s1, s2;
        if (ep == 0) { s1 = g1; s2 = g2; }
        else { s1 = 0.2f * s_old + 0.8f * g1; s2 = 0.2f * s_old + 0.8f * g2; }
        float pos = posdot[i];
        float l1 = f1 / (s1 * num_neg) - pos;
        float l2 = f2 / (s2 * num_neg) - pos;
        atomicAdd(out, (l1 + l2) * (1.0f / B_SZ));
        float gt1 = logf(s1) + RHO - f1 / (tau_i * s1 * num_neg);
        float gt2 = logf(s2) + RHO - f2 / (tau_i * s2 * num_neg);
        float gt = 0.5f * (gt1 + gt2);
        gt = fminf(fmaxf(gt, -3.0f), 3.0f);
        float u_new = 0.1f * u_old + 0.9f * gt;
        float tau_new = fminf(fmaxf(tau_i - 0.001f * u_new, 0.05f), 1.0f);
        if (ball == 0ULL) {  // winner (no later duplicate)
            out[1 + (size_t)idx] = 0.5f * (s1 + s2);
            out[1 + (size_t)N_TOT + idx] = u_new;
            out[1 + 2 * (size_t)N_TOT + idx] = tau_new;
        }
    }
}

extern "C" void kernel_launch(void* const* d_in, const int* in_sizes, int n_in,
                              void* d_out, int out_size, void* d_ws, size_t ws_size,
                              hipStream_t stream) {
    const float* features = (const float*)d_in[0];
    const float* s        = (const float*)d_in[1];
    const float* tau_buf  = (const float*)d_in[2];
    const float* u_buf    = (const float*)d_in[3];
    const int*   index    = (const int*)d_in[4];
    const int*   epoch    = (const int*)d_in[5];
    float* out = (float*)d_out;
    char* ws = (char*)d_ws;

    // workspace layout (~41.8 MB total)
    ushort_t* fbf          = (ushort_t*)(ws);                  // 8192*2048*2 = 33,554,432 B
    float*    inv_tau_rows = (float*)(ws + 33554432);          // 32 KB
    float*    Epart        = (float*)(ws + 33587200);          // 8192*128*4 = 4 MB
    float*    Fpart        = (float*)(ws + 37781504);          // 4 MB
    float*    posdot       = (float*)(ws + 41975808);          // 16 KB

    hipMemsetAsync(d_out, 0, sizeof(float), stream);   // zero loss accumulator

    knorm<<<TWO_B, 256, 0, stream>>>(features, fbf);
    ktau<<<TWO_B / 256, 256, 0, stream>>>(tau_buf, index, inv_tau_rows);
    kpos<<<B_SZ, 256, 0, stream>>>(fbf, posdot);
    kgram<<<dim3(64, 64), 256, 0, stream>>>(fbf, inv_tau_rows, Epart, Fpart);
    kcopy<<<2048, 256, 0, stream>>>(s, u_buf, tau_buf, out);
    kfin<<<B_SZ, 64, 0, stream>>>(Epart, Fpart, posdot, s, tau_buf, u_buf, index, epoch, out);
}

// Round 3
// 423.207 us; speedup vs baseline: 1.1851x; 1.1851x over previous
//
#include <hip/hip_runtime.h>
#include <hip/hip_bf16.h>
#include <stdint.h>

#define B_SZ   4096
#define TWO_B  8192
#define D_DIM  2048
#define N_TOT  15000000
#define RHO    0.8f
#define NT     32        // 2048 / 64 K-tiles
#define NRB    32        // 8192 / 256 row blocks
#define NBLK   528       // 32*33/2 upper-tri tiles

typedef __attribute__((ext_vector_type(8))) __bf16 bf16x8;
typedef __attribute__((ext_vector_type(4))) float f32x4;
typedef unsigned short ushort_t;

// ---------- helpers ----------
__device__ __forceinline__ ushort_t f2bf(float v) {
    __hip_bfloat16 h = __float2bfloat16(v);
    return *reinterpret_cast<ushort_t*>(&h);
}
__device__ __forceinline__ float bf2f(unsigned int u16) {
    return __uint_as_float(u16 << 16);
}
__device__ __forceinline__ float waveReduceSum(float v) {
#pragma unroll
    for (int off = 32; off >= 1; off >>= 1) v += __shfl_down(v, off, 64);
    return v;
}
__device__ __forceinline__ void gload_lds16(const void* g, void* l) {
    __builtin_amdgcn_global_load_lds(
        (const __attribute__((address_space(1))) void*)(uintptr_t)g,
        (__attribute__((address_space(3))) void*)(uintptr_t)l,
        16, 0, 0);
}

// ---------- kernel 1: normalize rows -> bf16 ----------
__global__ __launch_bounds__(256) void knorm(const float* __restrict__ feat,
                                             ushort_t* __restrict__ fbf) {
    int row = blockIdx.x;
    int tid = threadIdx.x;
    const float4* fr = reinterpret_cast<const float4*>(feat + (size_t)row * D_DIM);
    float4 a = fr[tid * 2 + 0];
    float4 b = fr[tid * 2 + 1];
    float ss = a.x*a.x + a.y*a.y + a.z*a.z + a.w*a.w
             + b.x*b.x + b.y*b.y + b.z*b.z + b.w*b.w;
    ss = waveReduceSum(ss);
    __shared__ float wsum[4];
    if ((tid & 63) == 0) wsum[tid >> 6] = ss;
    __syncthreads();
    float tot = wsum[0] + wsum[1] + wsum[2] + wsum[3];
    float inv = 1.0f / fmaxf(sqrtf(tot), 1e-12f);
    uint4 o;
    o.x = (unsigned)f2bf(a.x * inv) | ((unsigned)f2bf(a.y * inv) << 16);
    o.y = (unsigned)f2bf(a.z * inv) | ((unsigned)f2bf(a.w * inv) << 16);
    o.z = (unsigned)f2bf(b.x * inv) | ((unsigned)f2bf(b.y * inv) << 16);
    o.w = (unsigned)f2bf(b.z * inv) | ((unsigned)f2bf(b.w * inv) << 16);
    reinterpret_cast<uint4*>(fbf + (size_t)row * D_DIM)[tid] = o;
}

// ---------- kernel 2: inv_tau per sim row ----------
__global__ void ktau(const float* __restrict__ tau_buf, const int* __restrict__ index,
                     float* __restrict__ inv_tau_rows) {
    int i = blockIdx.x * blockDim.x + threadIdx.x;
    if (i < TWO_B) inv_tau_rows[i] = 1.0f / tau_buf[index[i & (B_SZ - 1)]];
}

// ---------- kernel 3: positive-pair dot ----------
__global__ __launch_bounds__(256) void kpos(const ushort_t* __restrict__ fbf,
                                            float* __restrict__ posdot) {
    int i = blockIdx.x;
    int tid = threadIdx.x;
    const uint4* r1 = reinterpret_cast<const uint4*>(fbf + (size_t)i * D_DIM);
    const uint4* r2 = reinterpret_cast<const uint4*>(fbf + (size_t)(i + B_SZ) * D_DIM);
    uint4 a = r1[tid], b = r2[tid];
    float s = 0.f;
    unsigned ua[4] = {a.x, a.y, a.z, a.w};
    unsigned ub[4] = {b.x, b.y, b.z, b.w};
#pragma unroll
    for (int k = 0; k < 4; ++k) {
        s += bf2f(ua[k] & 0xffffu) * bf2f(ub[k] & 0xffffu);
        s += bf2f(ua[k] >> 16)     * bf2f(ub[k] >> 16);
    }
    s = waveReduceSum(s);
    __shared__ float wsum[4];
    if ((tid & 63) == 0) wsum[tid >> 6] = s;
    __syncthreads();
    if (tid == 0) posdot[i] = wsum[0] + wsum[1] + wsum[2] + wsum[3];
}

// ---------- kernel 4: symmetric Gram, 256x256 tile, 8-wave, 4-phase/K-tile ----------
// Upper-tri tile grid (cb >= rb). Direct row-sums + transposed col-sums (cb>rb).
// LDS: 2-dbuf x (A 256x64 + B 256x64) bf16 = 128 KiB, XOR-swizzled chunks.
__global__ __launch_bounds__(512, 2) void kgram(const ushort_t* __restrict__ fbf,
                                                const float* __restrict__ itau,
                                                float* __restrict__ E,
                                                float* __restrict__ F) {
    int bid = (int)blockIdx.x;
    bid = (bid & 7) * (NBLK / 8) + (bid >> 3);        // XCD swizzle, 528 = 8*66
    int rb = 0, rem = bid;
    while (rem >= NRB - rb) { rem -= NRB - rb; ++rb; }
    const int cbb = rb + rem;                          // cb >= rb
    const int r0 = rb * 256, c0 = cbb * 256;

    const int tid = threadIdx.x;
    const int lane = tid & 63;
    const int w = tid >> 6;            // wave 0..7
    const int wr = w >> 2;             // 0..1  (M)
    const int wc = w & 3;              // 0..3  (N)
    const int l15 = lane & 15, lhi = lane >> 4, l7 = lane & 7;

    __shared__ ushort_t As[2][256 * 64];
    __shared__ ushort_t Bs[2][256 * 64];

    f32x4 acc[8][4] = {};

    // staging geometry: wave writes 8 rows x 64 cols per gload (64 lanes x 16B).
    // linear LDS dest (lane*16B); source chunk pre-swizzled: chunk ^= row&7.
    const int srow = lane >> 3;               // row within 8-row group
    const int schk = (lane & 7) ^ srow;       // swizzled global chunk

    // prologue: stage K-tile 0 into buf0
#pragma unroll
    for (int p = 0; p < 4; ++p) {
        int rowb = p * 64 + w * 8;
        gload_lds16(fbf + (size_t)(r0 + rowb + srow) * D_DIM + schk * 8, &As[0][rowb * 64]);
        gload_lds16(fbf + (size_t)(c0 + rowb + srow) * D_DIM + schk * 8, &Bs[0][rowb * 64]);
    }
    asm volatile("s_waitcnt vmcnt(0)" ::: "memory");
    __builtin_amdgcn_s_barrier();

    for (int t = 0; t < NT; ++t) {
        const int cur = t & 1;
        const bool pre = (t + 1 < NT);
        const int k0n = (t + 1) * 64;
        const ushort_t* __restrict__ A_l = &As[cur][0];
        const ushort_t* __restrict__ B_l = &Bs[cur][0];
#pragma unroll
        for (int p = 0; p < 4; ++p) {
            const int mh = p >> 1, nh = p & 1;
            bf16x8 af[4][2], bfr[2][2];
#pragma unroll
            for (int mi = 0; mi < 4; ++mi) {
                int rowl = wr * 128 + (mh * 4 + mi) * 16 + l15;
#pragma unroll
                for (int ks = 0; ks < 2; ++ks) {
                    int ch = ((ks * 32 + lhi * 8) >> 3) ^ l7;   // swizzled read chunk
                    af[mi][ks] = *reinterpret_cast<const bf16x8*>(&A_l[rowl * 64 + ch * 8]);
                }
            }
#pragma unroll
            for (int ni = 0; ni < 2; ++ni) {
                int rowl = wc * 64 + (nh * 2 + ni) * 16 + l15;
#pragma unroll
                for (int ks = 0; ks < 2; ++ks) {
                    int ch = ((ks * 32 + lhi * 8) >> 3) ^ l7;
                    bfr[ni][ks] = *reinterpret_cast<const bf16x8*>(&B_l[rowl * 64 + ch * 8]);
                }
            }
            if (pre) {
                int rowb = p * 64 + w * 8;
                gload_lds16(fbf + (size_t)(r0 + rowb + srow) * D_DIM + k0n + schk * 8,
                            &As[cur ^ 1][rowb * 64]);
                gload_lds16(fbf + (size_t)(c0 + rowb + srow) * D_DIM + k0n + schk * 8,
                            &Bs[cur ^ 1][rowb * 64]);
            }
            __builtin_amdgcn_s_barrier();
            asm volatile("s_waitcnt lgkmcnt(0)" ::: "memory");
            __builtin_amdgcn_sched_barrier(0);
            __builtin_amdgcn_s_setprio(1);
#pragma unroll
            for (int mi = 0; mi < 4; ++mi)
#pragma unroll
                for (int ni = 0; ni < 2; ++ni)
#pragma unroll
                    for (int ks = 0; ks < 2; ++ks)
                        acc[mh * 4 + mi][nh * 2 + ni] = __builtin_amdgcn_mfma_f32_16x16x32_bf16(
                            af[mi][ks], bfr[ni][ks], acc[mh * 4 + mi][nh * 2 + ni], 0, 0, 0);
            __builtin_amdgcn_s_setprio(0);
            if (p == 3) {   // drain next tile's stages before its reads (once per K-tile)
                asm volatile("s_waitcnt vmcnt(0)" ::: "memory");
                __builtin_amdgcn_sched_barrier(0);
            }
            __builtin_amdgcn_s_barrier();
        }
    }

    // ---- epilogue: direct row-sums (exp with row tau) ----
#pragma unroll
    for (int m = 0; m < 8; ++m) {
#pragma unroll
        for (int r = 0; r < 4; ++r) {
            int row_g = r0 + wr * 128 + m * 16 + lhi * 4 + r;
            float it = itau[row_g];
            float e = 0.f, f = 0.f;
#pragma unroll
            for (int n = 0; n < 4; ++n) {
                int col_g = c0 + wc * 64 + n * 16 + l15;
                float v = acc[m][n][r];
                if (((row_g ^ col_g) & (B_SZ - 1)) != 0) {
                    float ex = __expf(v * it);
                    e += ex;
                    f += ex * v;
                }
            }
#pragma unroll
            for (int off = 1; off < 16; off <<= 1) {
                e += __shfl_xor(e, off, 64);
                f += __shfl_xor(f, off, 64);
            }
            if (l15 == 0) {
                atomicAdd(&E[row_g], e);
                atomicAdd(&F[row_g], f);
            }
        }
    }
    // ---- transposed col-sums (exp with col tau), off-diagonal tiles only ----
    if (cbb != rb) {
#pragma unroll
        for (int n = 0; n < 4; ++n) {
            int colT = c0 + wc * 64 + n * 16 + l15;   // sim row for transposed part
            float it = itau[colT];
            float e = 0.f, f = 0.f;
#pragma unroll
            for (int m = 0; m < 8; ++m) {
#pragma unroll
                for (int r = 0; r < 4; ++r) {
                    int row_g = r0 + wr * 128 + m * 16 + lhi * 4 + r;  // summation index
                    float v = acc[m][n][r];
                    if (((row_g ^ colT) & (B_SZ - 1)) != 0) {
                        float ex = __expf(v * it);
                        e += ex;
                        f += ex * v;
                    }
                }
            }
            e += __shfl_xor(e, 16, 64);
            f += __shfl_xor(f, 16, 64);
            e += __shfl_xor(e, 32, 64);
            f += __shfl_xor(f, 32, 64);
            if (lhi == 0) {
                atomicAdd(&E[colT], e);
                atomicAdd(&F[colT], f);
            }
        }
    }
}

// ---------- kernel 5: bulk copy s/u/tau -> out (float4 loads) ----------
typedef float4 __attribute__((aligned(4))) float4u;
__global__ void kcopy(const float4* __restrict__ s, const float4* __restrict__ u,
                      const float4* __restrict__ tau, float* __restrict__ out) {
    size_t i = (size_t)blockIdx.x * blockDim.x + threadIdx.x;
    size_t stride = (size_t)gridDim.x * blockDim.x;
    const size_t n4 = N_TOT / 4;
    for (; i < n4; i += stride) {
        *reinterpret_cast<float4u*>(out + 1 + 4 * i) = s[i];
        *reinterpret_cast<float4u*>(out + 1 + (size_t)N_TOT + 4 * i) = u[i];
        *reinterpret_cast<float4u*>(out + 1 + 2 * (size_t)N_TOT + 4 * i) = tau[i];
    }
}

// ---------- kernel 6: finalize per positive pair ----------
__global__ __launch_bounds__(64) void kfin(const float* __restrict__ E,
                                           const float* __restrict__ F,
                                           const float* __restrict__ posdot,
                                           const float* __restrict__ s,
                                           const float* __restrict__ tau_buf,
                                           const float* __restrict__ u_buf,
                                           const int* __restrict__ index,
                                           const int* __restrict__ epoch_p,
                                           float* __restrict__ out) {
    int i = blockIdx.x;     // [0, B)
    int lane = threadIdx.x; // [0, 64)
    int idx = index[i];
    bool dup = false;
    for (int j = i + 1 + lane; j < B_SZ; j += 64)
        if (index[j] == idx) dup = true;
    unsigned long long ball = __ballot(dup);

    if (lane == 0) {
        float e1 = E[i], f1 = F[i];
        float e2 = E[i + B_SZ], f2 = F[i + B_SZ];
        const float num_neg = 2.0f * B_SZ - 2.0f;
        float g1 = e1 / num_neg, g2 = e2 / num_neg;
        float s_old = s[idx];
        float tau_i = tau_buf[idx];
        float u_old = u_buf[idx];
        int ep = *epoch_p;
        float s1, s2;
        if (ep == 0) { s1 = g1; s2 = g2; }
        else { s1 = 0.2f * s_old + 0.8f * g1; s2 = 0.2f * s_old + 0.8f * g2; }
        float pos = posdot[i];
        float l1 = f1 / (s1 * num_neg) - pos;
        float l2 = f2 / (s2 * num_neg) - pos;
        atomicAdd(out, (l1 + l2) * (1.0f / B_SZ));
        float gt1 = logf(s1) + RHO - f1 / (tau_i * s1 * num_neg);
        float gt2 = logf(s2) + RHO - f2 / (tau_i * s2 * num_neg);
        float gt = 0.5f * (gt1 + gt2);
        gt = fminf(fmaxf(gt, -3.0f), 3.0f);
        float u_new = 0.1f * u_old + 0.9f * gt;
        float tau_new = fminf(fmaxf(tau_i - 0.001f * u_new, 0.05f), 1.0f);
        if (ball == 0ULL) {  // winner (numpy last-wins)
            out[1 + (size_t)idx] = 0.5f * (s1 + s2);
            out[1 + (size_t)N_TOT + idx] = u_new;
            out[1 + 2 * (size_t)N_TOT + idx] = tau_new;
        }
    }
}

extern "C" void kernel_launch(void* const* d_in, const int* in_sizes, int n_in,
                              void* d_out, int out_size, void* d_ws, size_t ws_size,
                              hipStream_t stream) {
    const float* features = (const float*)d_in[0];
    const float* s        = (const float*)d_in[1];
    const float* tau_buf  = (const float*)d_in[2];
    const float* u_buf    = (const float*)d_in[3];
    const int*   index    = (const int*)d_in[4];
    const int*   epoch    = (const int*)d_in[5];
    float* out = (float*)d_out;
    char* ws = (char*)d_ws;

    // workspace layout
    ushort_t* fbf          = (ushort_t*)(ws);                  // 33,554,432 B
    float*    inv_tau_rows = (float*)(ws + 33554432);          // 32 KB
    float*    E            = (float*)(ws + 33587200);          // 32 KB
    float*    F            = (float*)(ws + 33619968);          // 32 KB
    float*    posdot       = (float*)(ws + 33652736);          // 16 KB

    hipMemsetAsync(d_out, 0, sizeof(float), stream);           // loss accumulator
    hipMemsetAsync(E, 0, 2 * TWO_B * sizeof(float), stream);   // E and F (contiguous)

    knorm<<<TWO_B, 256, 0, stream>>>(features, fbf);
    ktau<<<TWO_B / 256, 256, 0, stream>>>(tau_buf, index, inv_tau_rows);
    kpos<<<B_SZ, 256, 0, stream>>>(fbf, posdot);
    kgram<<<NBLK, 512, 0, stream>>>(fbf, inv_tau_rows, E, F);
    kcopy<<<2048, 256, 0, stream>>>((const float4*)s, (const float4*)u_buf,
                                    (const float4*)tau_buf, out);
    kfin<<<B_SZ, 64, 0, stream>>>(E, F, posdot, s, tau_buf, u_buf, index, epoch, out);
}

// Round 4
// 326.577 us; speedup vs baseline: 1.5358x; 1.2959x over previous
//
#include <hip/hip_runtime.h>
#include <hip/hip_bf16.h>
#include <stdint.h>

#define B_SZ   4096
#define TWO_B  8192
#define D_DIM  2048
#define N_TOT  15000000
#define RHO    0.8f
#define NT     64         // 2048 / 32 K-tiles
#define NJOB   1056       // sum_{C=0}^{31} (2C+2) jobs of 128x256
#define GRAM_THREADS 512

typedef __attribute__((ext_vector_type(8))) __bf16 bf16x8;
typedef __attribute__((ext_vector_type(4))) float f32x4;
typedef unsigned short ushort_t;

// ---------- helpers ----------
__device__ __forceinline__ ushort_t f2bf(float v) {
    __hip_bfloat16 h = __float2bfloat16(v);
    return *reinterpret_cast<ushort_t*>(&h);
}
__device__ __forceinline__ float bf2f(unsigned int u16) {
    return __uint_as_float(u16 << 16);
}
__device__ __forceinline__ float waveReduceSum(float v) {
#pragma unroll
    for (int off = 32; off >= 1; off >>= 1) v += __shfl_down(v, off, 64);
    return v;
}
__device__ __forceinline__ void gload_lds16(const void* g, void* l) {
    __builtin_amdgcn_global_load_lds(
        (const __attribute__((address_space(1))) void*)(uintptr_t)g,
        (__attribute__((address_space(3))) void*)(uintptr_t)l,
        16, 0, 0);
}

// ---------- kernel 1: normalize rows -> bf16 ----------
__global__ __launch_bounds__(256) void knorm(const float* __restrict__ feat,
                                             ushort_t* __restrict__ fbf) {
    int row = blockIdx.x;
    int tid = threadIdx.x;
    const float4* fr = reinterpret_cast<const float4*>(feat + (size_t)row * D_DIM);
    float4 a = fr[tid * 2 + 0];
    float4 b = fr[tid * 2 + 1];
    float ss = a.x*a.x + a.y*a.y + a.z*a.z + a.w*a.w
             + b.x*b.x + b.y*b.y + b.z*b.z + b.w*b.w;
    ss = waveReduceSum(ss);
    __shared__ float wsum[4];
    if ((tid & 63) == 0) wsum[tid >> 6] = ss;
    __syncthreads();
    float tot = wsum[0] + wsum[1] + wsum[2] + wsum[3];
    float inv = 1.0f / fmaxf(sqrtf(tot), 1e-12f);
    uint4 o;
    o.x = (unsigned)f2bf(a.x * inv) | ((unsigned)f2bf(a.y * inv) << 16);
    o.y = (unsigned)f2bf(a.z * inv) | ((unsigned)f2bf(a.w * inv) << 16);
    o.z = (unsigned)f2bf(b.x * inv) | ((unsigned)f2bf(b.y * inv) << 16);
    o.w = (unsigned)f2bf(b.z * inv) | ((unsigned)f2bf(b.w * inv) << 16);
    reinterpret_cast<uint4*>(fbf + (size_t)row * D_DIM)[tid] = o;
}

// ---------- kernel 2: inv_tau per sim row ----------
__global__ void ktau(const float* __restrict__ tau_buf, const int* __restrict__ index,
                     float* __restrict__ inv_tau_rows) {
    int i = blockIdx.x * blockDim.x + threadIdx.x;
    if (i < TWO_B) inv_tau_rows[i] = 1.0f / tau_buf[index[i & (B_SZ - 1)]];
}

// ---------- kernel 3: positive-pair dot ----------
__global__ __launch_bounds__(256) void kpos(const ushort_t* __restrict__ fbf,
                                            float* __restrict__ posdot) {
    int i = blockIdx.x;
    int tid = threadIdx.x;
    const uint4* r1 = reinterpret_cast<const uint4*>(fbf + (size_t)i * D_DIM);
    const uint4* r2 = reinterpret_cast<const uint4*>(fbf + (size_t)(i + B_SZ) * D_DIM);
    uint4 a = r1[tid], b = r2[tid];
    float s = 0.f;
    unsigned ua[4] = {a.x, a.y, a.z, a.w};
    unsigned ub[4] = {b.x, b.y, b.z, b.w};
#pragma unroll
    for (int k = 0; k < 4; ++k) {
        s += bf2f(ua[k] & 0xffffu) * bf2f(ub[k] & 0xffffu);
        s += bf2f(ua[k] >> 16)     * bf2f(ub[k] >> 16);
    }
    s = waveReduceSum(s);
    __shared__ float wsum[4];
    if ((tid & 63) == 0) wsum[tid >> 6] = s;
    __syncthreads();
    if (tid == 0) posdot[i] = wsum[0] + wsum[1] + wsum[2] + wsum[3];
}

// ---------- kernel 4: symmetric Gram, 128x256 jobs, BK=32, triple-buffer,
//            counted vmcnt(3), fused masked-exp reductions + fused s/u/tau copy.
// Job (R,C): rows 128R..128R+127, cols 256C..256C+255, exists iff C >= R>>1.
// Per element with col>row: E[row] += exp(v*itau[row]) (+F), E[col] += exp(v*itau[col]) (+F).
__global__ __launch_bounds__(GRAM_THREADS, 4) void kgram(
        const ushort_t* __restrict__ fbf, const float* __restrict__ itau,
        float* __restrict__ E, float* __restrict__ F,
        const float4* __restrict__ sIn, const float4* __restrict__ uIn,
        const float4* __restrict__ tIn, float* __restrict__ out) {
    const int raw = (int)blockIdx.x;
    const int bid = (raw & 7) * (NJOB / 8) + (raw >> 3);   // XCD swizzle (1056 = 8*132)
    // decode job: largest C with C*C+C <= bid; R = bid - C*C - C
    int C = (int)((sqrtf((float)(4 * bid + 1)) - 1.0f) * 0.5f);
    while (C * C + C > bid) --C;
    while ((C + 1) * (C + 1) + (C + 1) <= bid) ++C;
    const int R = bid - C * C - C;
    const int r0 = R * 128, c0 = C * 256;

    const int tid = threadIdx.x;
    const int lane = tid & 63;
    const int w = tid >> 6;            // wave 0..7
    const int wr = w >> 2;             // 0..1 (M)
    const int wc = w & 3;              // 0..3 (N)
    const int l15 = lane & 15, lhi = lane >> 4;

    __shared__ alignas(16) ushort_t As[3][128 * 32];
    __shared__ alignas(16) ushort_t Bs[3][256 * 32];

    f32x4 acc[4][4] = {};

    // staging: one wave-gload fills 16 rows x 32 cols (64 lanes x 16B), linear LDS.
    // swizzle via source: global chunk = (l&3) ^ ((l>>3)&3)  [key = (rowLocal>>1)&3]
    const int srow = lane >> 2;
    const int schk = (lane & 3) ^ ((lane >> 3) & 3);
    const uint32_t gA  = (uint32_t)(r0 + w * 16 + srow) * D_DIM + schk * 8;
    const uint32_t gB0 = (uint32_t)(c0 + w * 32 + srow) * D_DIM + schk * 8;
    const uint32_t gB1 = gB0 + 16u * D_DIM;
    const int lA  = w * 16 * 32;       // element offsets into As[buf]/Bs[buf]
    const int lB0 = w * 32 * 32;
    const int lB1 = (w * 32 + 16) * 32;

#define STAGE(buf, t)                                                    \
    do {                                                                 \
        uint32_t k_ = (uint32_t)(t) * 32u;                               \
        gload_lds16(fbf + gA + k_,  &As[buf][lA]);                       \
        gload_lds16(fbf + gB0 + k_, &Bs[buf][lB0]);                      \
        gload_lds16(fbf + gB1 + k_, &Bs[buf][lB1]);                      \
    } while (0)

    // prologue: stage tiles 0,1; ensure tile 0 landed (keep tile 1 in flight)
    STAGE(0, 0);
    STAGE(1, 1);
    asm volatile("s_waitcnt vmcnt(3)" ::: "memory");
    __builtin_amdgcn_sched_barrier(0);
    __builtin_amdgcn_s_barrier();

    const int rdch = (lhi ^ ((l15 >> 1) & 3)) * 8;   // swizzled read chunk (elements)
    int bufc = 0;
    for (int t = 0; t < NT; ++t) {
        if (t + 2 < NT) {
            int bw = (bufc >= 1) ? bufc - 1 : 2;     // (bufc+2)%3
            STAGE(bw, t + 2);
        }
        const ushort_t* __restrict__ A_l = &As[bufc][0];
        const ushort_t* __restrict__ B_l = &Bs[bufc][0];
        bf16x8 af[4], bfr[4];
#pragma unroll
        for (int m = 0; m < 4; ++m)
            af[m] = *reinterpret_cast<const bf16x8*>(&A_l[(wr * 64 + m * 16 + l15) * 32 + rdch]);
#pragma unroll
        for (int n = 0; n < 4; ++n)
            bfr[n] = *reinterpret_cast<const bf16x8*>(&B_l[(wc * 64 + n * 16 + l15) * 32 + rdch]);
        __builtin_amdgcn_s_setprio(1);
#pragma unroll
        for (int m = 0; m < 4; ++m)
#pragma unroll
            for (int n = 0; n < 4; ++n)
                acc[m][n] = __builtin_amdgcn_mfma_f32_16x16x32_bf16(af[m], bfr[n], acc[m][n], 0, 0, 0);
        __builtin_amdgcn_s_setprio(0);
        if (t < NT - 2) {
            asm volatile("s_waitcnt vmcnt(3)" ::: "memory");   // next tile ready; deeper loads fly
        } else if (t == NT - 2) {
            asm volatile("s_waitcnt vmcnt(0)" ::: "memory");   // last tile's loads
        }
        __builtin_amdgcn_sched_barrier(0);
        if (t < NT - 1) __builtin_amdgcn_s_barrier();
        bufc = (bufc == 2) ? 0 : bufc + 1;
    }
#undef STAGE

    // ---- epilogue: per element col>row -> direct (row tau) + transposed (col tau) ----
#pragma unroll
    for (int m = 0; m < 4; ++m) {
#pragma unroll
        for (int r = 0; r < 4; ++r) {
            int row_g = r0 + wr * 64 + m * 16 + lhi * 4 + r;
            float it = itau[row_g];
            float e = 0.f, f = 0.f;
#pragma unroll
            for (int n = 0; n < 4; ++n) {
                int col_g = c0 + wc * 64 + n * 16 + l15;
                float v = acc[m][n][r];
                if (col_g > row_g && (((row_g ^ col_g) & (B_SZ - 1)) != 0)) {
                    float ex = __expf(v * it);
                    e += ex;
                    f += ex * v;
                }
            }
#pragma unroll
            for (int off = 1; off < 16; off <<= 1) {
                e += __shfl_xor(e, off, 64);
                f += __shfl_xor(f, off, 64);
            }
            if (l15 == 0) {
                atomicAdd(&E[row_g], e);
                atomicAdd(&F[row_g], f);
            }
        }
    }
#pragma unroll
    for (int n = 0; n < 4; ++n) {
        int colT = c0 + wc * 64 + n * 16 + l15;
        float it = itau[colT];
        float e = 0.f, f = 0.f;
#pragma unroll
        for (int m = 0; m < 4; ++m) {
#pragma unroll
            for (int r = 0; r < 4; ++r) {
                int row_g = r0 + wr * 64 + m * 16 + lhi * 4 + r;
                float v = acc[m][n][r];
                if (colT > row_g && (((row_g ^ colT) & (B_SZ - 1)) != 0)) {
                    float ex = __expf(v * it);
                    e += ex;
                    f += ex * v;
                }
            }
        }
        e += __shfl_xor(e, 16, 64);
        f += __shfl_xor(f, 16, 64);
        e += __shfl_xor(e, 32, 64);
        f += __shfl_xor(f, 32, 64);
        if (lhi == 0) {
            atomicAdd(&E[colT], e);
            atomicAdd(&F[colT], f);
        }
    }

    // ---- fused bulk copy s/u/tau -> out (overlaps other blocks' compute) ----
    {
        typedef float4 __attribute__((aligned(4))) float4u;
        size_t i = (size_t)raw * GRAM_THREADS + tid;
        const size_t stride = (size_t)NJOB * GRAM_THREADS;
        const size_t n4 = N_TOT / 4;
        for (; i < n4; i += stride) {
            *reinterpret_cast<float4u*>(out + 1 + 4 * i) = sIn[i];
            *reinterpret_cast<float4u*>(out + 1 + (size_t)N_TOT + 4 * i) = uIn[i];
            *reinterpret_cast<float4u*>(out + 1 + 2 * (size_t)N_TOT + 4 * i) = tIn[i];
        }
    }
}

// ---------- kernel 6: finalize per positive pair ----------
__global__ __launch_bounds__(64) void kfin(const float* __restrict__ E,
                                           const float* __restrict__ F,
                                           const float* __restrict__ posdot,
                                           const float* __restrict__ s,
                                           const float* __restrict__ tau_buf,
                                           const float* __restrict__ u_buf,
                                           const int* __restrict__ index,
                                           const int* __restrict__ epoch_p,
                                           float* __restrict__ out) {
    int i = blockIdx.x;     // [0, B)
    int lane = threadIdx.x; // [0, 64)
    int idx = index[i];
    bool dup = false;
    for (int j = i + 1 + lane; j < B_SZ; j += 64)
        if (index[j] == idx) dup = true;
    unsigned long long ball = __ballot(dup);

    if (lane == 0) {
        float e1 = E[i], f1 = F[i];
        float e2 = E[i + B_SZ], f2 = F[i + B_SZ];
        const float num_neg = 2.0f * B_SZ - 2.0f;
        float g1 = e1 / num_neg, g2 = e2 / num_neg;
        float s_old = s[idx];
        float tau_i = tau_buf[idx];
        float u_old = u_buf[idx];
        int ep = *epoch_p;
        float s1, s2;
        if (ep == 0) { s1 = g1; s2 = g2; }
        else { s1 = 0.2f * s_old + 0.8f * g1; s2 = 0.2f * s_old + 0.8f * g2; }
        float pos = posdot[i];
        float l1 = f1 / (s1 * num_neg) - pos;
        float l2 = f2 / (s2 * num_neg) - pos;
        atomicAdd(out, (l1 + l2) * (1.0f / B_SZ));
        float gt1 = logf(s1) + RHO - f1 / (tau_i * s1 * num_neg);
        float gt2 = logf(s2) + RHO - f2 / (tau_i * s2 * num_neg);
        float gt = 0.5f * (gt1 + gt2);
        gt = fminf(fmaxf(gt, -3.0f), 3.0f);
        float u_new = 0.1f * u_old + 0.9f * gt;
        float tau_new = fminf(fmaxf(tau_i - 0.001f * u_new, 0.05f), 1.0f);
        if (ball == 0ULL) {  // winner (numpy last-wins)
            out[1 + (size_t)idx] = 0.5f * (s1 + s2);
            out[1 + (size_t)N_TOT + idx] = u_new;
            out[1 + 2 * (size_t)N_TOT + idx] = tau_new;
        }
    }
}

extern "C" void kernel_launch(void* const* d_in, const int* in_sizes, int n_in,
                              void* d_out, int out_size, void* d_ws, size_t ws_size,
                              hipStream_t stream) {
    const float* features = (const float*)d_in[0];
    const float* s        = (const float*)d_in[1];
    const float* tau_buf  = (const float*)d_in[2];
    const float* u_buf    = (const float*)d_in[3];
    const int*   index    = (const int*)d_in[4];
    const int*   epoch    = (const int*)d_in[5];
    float* out = (float*)d_out;
    char* ws = (char*)d_ws;

    // workspace layout
    ushort_t* fbf          = (ushort_t*)(ws);                  // 33,554,432 B
    float*    inv_tau_rows = (float*)(ws + 33554432);          // 32 KB
    float*    E            = (float*)(ws + 33587200);          // 32 KB
    float*    F            = (float*)(ws + 33619968);          // 32 KB
    float*    posdot       = (float*)(ws + 33652736);          // 16 KB

    hipMemsetAsync(d_out, 0, sizeof(float), stream);           // loss accumulator
    hipMemsetAsync(E, 0, 2 * TWO_B * sizeof(float), stream);   // E and F (contiguous)

    knorm<<<TWO_B, 256, 0, stream>>>(features, fbf);
    ktau<<<TWO_B / 256, 256, 0, stream>>>(tau_buf, index, inv_tau_rows);
    kpos<<<B_SZ, 256, 0, stream>>>(fbf, posdot);
    kgram<<<NJOB, GRAM_THREADS, 0, stream>>>(fbf, inv_tau_rows, E, F,
                                             (const float4*)s, (const float4*)u_buf,
                                             (const float4*)tau_buf, out);
    kfin<<<B_SZ, 64, 0, stream>>>(E, F, posdot, s, tau_buf, u_buf, index, epoch, out);
}